// Round 6
// baseline (595.795 us; speedup 1.0000x reference)
//
#include <hip/hip_runtime.h>
#include <math.h>

#define BB 8
#define NN 4096
#define DD 1024
#define PP 16
#define KS 8           // k-split for e-step
#define KC (DD / KS)   // 128 k per chunk

static constexpr float DLOG2PI = 1881.9861160031696f; // 1024 * log(2*pi)
static constexpr float EPSC = 0.1f;

// W layout: Wmat[b][k][32] interleaved pairs: [j*2]=invS_j(k), [j*2+1]=mu_j(k)*invS_j(k)
// (j 0..7 -> floats 0..15, j 8..15 -> floats 16..31: j-half = contiguous 64B)
// Wmat/qq accesses in hot kernels are wave-uniform -> scalar (s_load) path.
// NOTE (R3): never take a pointer/reference to per-thread accumulator arrays
// — address-taking forces them to scratch (VGPR=32 + GBs of spill).
// NOTE (R4/R5): latency-bound, not VALU-bound. Occupancy (waves/CU) is the
// lever; split the j (accumulator) dimension to add blocks without growing
// any intermediate buffer.

#define FELEM(v, c) ((c) == 0 ? (v).x : (c) == 1 ? (v).y : (c) == 2 ? (v).z : (v).w)

// ---------------------------------------------------------------------------
// k_init: build Wmat + cns[b][j] = log pi - 0.5*(d log2pi + sum log S + sum mu^2/S)
// grid (16 j, 8 b), 256 threads (4 d each)
// ---------------------------------------------------------------------------
__global__ __launch_bounds__(256) void k_init(const float* __restrict__ m,
                                              const float* __restrict__ V_,
                                              float* __restrict__ Wmat,
                                              float* __restrict__ cns)
{
    int j = blockIdx.x, b = blockIdx.y;
    int tid = threadIdx.x;
    __shared__ float red[512];
    int d0 = tid * 4;
    float4 m4 = *(const float4*)(m + j * DD + d0);
    float4 v4 = *(const float4*)(V_ + j * DD + d0);
    float mv[4] = {m4.x, m4.y, m4.z, m4.w};
    float vv[4] = {v4.x, v4.y, v4.z, v4.w};
    float* Wb = Wmat + (size_t)b * (DD * 32);
    float llog = 0.f, lmq = 0.f;
#pragma unroll
    for (int c = 0; c < 4; c++) {
        float V = EPSC * log1pf(expf(vv[c]));
        float inv = 1.0f / V;
        int d = d0 + c;
        Wb[d * 32 + j * 2] = inv;
        Wb[d * 32 + j * 2 + 1] = mv[c] * inv;
        llog += logf(V);
        lmq += mv[c] * mv[c] * inv;
    }
    red[tid] = llog; red[256 + tid] = lmq;
    __syncthreads();
    for (int s = 128; s > 0; s >>= 1) {
        if (tid < s) { red[tid] += red[tid + s]; red[256 + tid] += red[256 + tid + s]; }
        __syncthreads();
    }
    if (tid == 0)
        cns[b * PP + j] = logf(1.0f / 16.0f) - 0.5f * (DLOG2PI + red[0] + red[256]);
}

// ---------------------------------------------------------------------------
// k_estep: NO LDS. Thread owns TWO rows x EIGHT j, one 128-k chunk. W via
// s_load (one dwordx16 per k-subgroup); X explicitly double-buffered.
// grid (16 = rb*2+jh, 8 ks, 8 b) = 1024 blocks, 256 threads.
// writes epart[ks][b][n][j-half] = -0.5*S1 + S2 partial.
// ---------------------------------------------------------------------------
__global__ __launch_bounds__(256) void k_estep(const float* __restrict__ X,
                                               const float* __restrict__ Wmat,
                                               float* __restrict__ epart)
{
    int bx = blockIdx.x;
    int rb = bx >> 1, jh = bx & 1;
    int ks = blockIdx.y, b = blockIdx.z;
    int tid = threadIdx.x;
    int n0 = rb * 512 + tid * 2;   // rows n0, n0+1
    const float* xp0 = X + ((size_t)b * NN + n0) * DD + ks * KC;
    const float* xp1 = xp0 + DD;
    const float* wp = Wmat + (size_t)b * (DD * 32) + (size_t)(ks * KC) * 32 + jh * 16;
    float a1[2][8] = {};
    float a2[2][8] = {};
    float4 cur[8], nxt[8];

#define ESTEP_LOAD(BUF, T)                                                     \
    _Pragma("unroll")                                                          \
    for (int u = 0; u < 4; u++) {                                              \
        BUF[u]     = *(const float4*)(xp0 + (T) * 16 + u * 4);                 \
        BUF[4 + u] = *(const float4*)(xp1 + (T) * 16 + u * 4);                 \
    }

#define ESTEP_COMPUTE(BUF, T)                                                  \
    _Pragma("unroll")                                                          \
    for (int u = 0; u < 4; u++) {                                              \
        _Pragma("unroll")                                                      \
        for (int c = 0; c < 4; c++) {                                          \
            const float* wk = wp + ((T) * 16 + u * 4 + c) * 32;                \
            float xv0 = FELEM(BUF[u], c),     xq0 = xv0 * xv0;                 \
            float xv1 = FELEM(BUF[4 + u], c), xq1 = xv1 * xv1;                 \
            _Pragma("unroll")                                                  \
            for (int j = 0; j < 8; j++) {                                      \
                a1[0][j] = fmaf(xq0, wk[2 * j],     a1[0][j]);                 \
                a2[0][j] = fmaf(xv0, wk[2 * j + 1], a2[0][j]);                 \
                a1[1][j] = fmaf(xq1, wk[2 * j],     a1[1][j]);                 \
                a2[1][j] = fmaf(xv1, wk[2 * j + 1], a2[1][j]);                 \
            }                                                                  \
        }                                                                      \
    }

    ESTEP_LOAD(cur, 0)
#pragma unroll 1
    for (int t = 0; t < 8; t += 2) {
        ESTEP_LOAD(nxt, t + 1)
        ESTEP_COMPUTE(cur, t)
        int t2 = (t + 2 < 8) ? t + 2 : 0;   // wrap: harmless reload, unused
        ESTEP_LOAD(cur, t2)
        ESTEP_COMPUTE(nxt, t + 1)
    }
#undef ESTEP_LOAD
#undef ESTEP_COMPUTE

    float* ep = epart + (((size_t)ks * BB + b) * NN + n0) * PP + jh * 8;
#pragma unroll
    for (int r = 0; r < 2; r++) {
#pragma unroll
        for (int q = 0; q < 2; q++) {
            float4 v = make_float4(-0.5f * a1[r][q * 4 + 0] + a2[r][q * 4 + 0],
                                   -0.5f * a1[r][q * 4 + 1] + a2[r][q * 4 + 1],
                                   -0.5f * a1[r][q * 4 + 2] + a2[r][q * 4 + 2],
                                   -0.5f * a1[r][q * 4 + 3] + a2[r][q * 4 + 3]);
            *(float4*)(ep + r * PP + q * 4) = v;
        }
    }
}

// ---------------------------------------------------------------------------
// k_ereduce: sum KS k-partials + cns, softmax over 16 j, * mask -> qq.
// Also emits per-block wsum partial wsum_p[b][chunk][16].
// grid (32 chunks of 128 rows, 8 b), 128 threads (1 row each)
// ---------------------------------------------------------------------------
__global__ __launch_bounds__(128) void k_ereduce(const float* __restrict__ epart,
                                                 const float* __restrict__ mask,
                                                 const float* __restrict__ cns,
                                                 float* __restrict__ qq,
                                                 float* __restrict__ wsum_p)
{
    int chunk = blockIdx.x, b = blockIdx.y;
    int tid = threadIdx.x;
    int n = chunk * 128 + tid;
    __shared__ float cs[16];
    __shared__ float red[128 * 17];
    if (tid < 16) cs[tid] = cns[b * PP + tid];
    __syncthreads();
    float jl[16];
#pragma unroll
    for (int q = 0; q < 4; q++) {
        float4 v = *(const float4*)(epart + ((size_t)b * NN + n) * PP + q * 4);
        jl[q * 4 + 0] = v.x; jl[q * 4 + 1] = v.y; jl[q * 4 + 2] = v.z; jl[q * 4 + 3] = v.w;
    }
#pragma unroll
    for (int ks = 1; ks < KS; ks++) {
#pragma unroll
        for (int q = 0; q < 4; q++) {
            float4 v = *(const float4*)(epart + (((size_t)ks * BB + b) * NN + n) * PP + q * 4);
            jl[q * 4 + 0] += v.x; jl[q * 4 + 1] += v.y; jl[q * 4 + 2] += v.z; jl[q * 4 + 3] += v.w;
        }
    }
    float mx = -3.4e38f;
#pragma unroll
    for (int j = 0; j < 16; j++) { jl[j] += cs[j]; mx = fmaxf(mx, jl[j]); }
    float sum = 0.f;
#pragma unroll
    for (int j = 0; j < 16; j++) { jl[j] = expf(jl[j] - mx); sum += jl[j]; }
    float r = mask[(size_t)b * NN + n] / sum;
    float* qo = qq + ((size_t)b * NN + n) * PP;
#pragma unroll
    for (int q = 0; q < 4; q++) {
        float4 v = make_float4(jl[q * 4 + 0] * r, jl[q * 4 + 1] * r,
                               jl[q * 4 + 2] * r, jl[q * 4 + 3] * r);
        *(float4*)(qo + q * 4) = v;
        red[tid * 17 + q * 4 + 0] = v.x;
        red[tid * 17 + q * 4 + 1] = v.y;
        red[tid * 17 + q * 4 + 2] = v.z;
        red[tid * 17 + q * 4 + 3] = v.w;
    }
    __syncthreads();
    if (tid < 16) {
        float s = 0.f;
#pragma unroll 8
        for (int t = 0; t < 128; t++) s += red[t * 17 + tid];
        wsum_p[((size_t)b * 32 + chunk) * 16 + tid] = s;
    }
}

// ---------------------------------------------------------------------------
// k_mstep: NO LDS in hot loop. Thread = 4 cols x 8 j (x2 arrays) = 64 accs.
// Block of 512: all 1024 cols x 2 n-phases for one j-half.
// qq row wave-uniform -> s_load. Explicit X double-buffer.
// grid (2 jh, 32 nq of 128 rows, 8 b) = 512 blocks.
// ---------------------------------------------------------------------------
__global__ __launch_bounds__(512) void k_mstep(const float* __restrict__ X,
                                               const float* __restrict__ qq,
                                               float* __restrict__ wxp,
                                               float* __restrict__ wxxp)
{
    int jh = blockIdx.x, nq = blockIdx.y, b = blockIdx.z;
    int jbase = jh * 8;
    int tid = threadIdx.x;
    int cg = tid & 255;      // col group: 4 cols
    int ph = tid >> 8;       // 0/1 (wave-uniform)
    int col0 = cg * 4;
    const float* Xb = X + (size_t)b * NN * DD;
    const float* qb = qq + (size_t)b * NN * PP + jbase;
    int nbase = nq * 128 + ph;
    float aw[8][4] = {};
    float ax[8][4] = {};

#define MSTEP_FMA(XV, QP)                                                      \
    {                                                                          \
        float x2x = (XV).x * (XV).x, x2y = (XV).y * (XV).y;                    \
        float x2z = (XV).z * (XV).z, x2w = (XV).w * (XV).w;                    \
        _Pragma("unroll")                                                      \
        for (int j = 0; j < 8; j++) {                                          \
            float qj = (QP)[j];                                                \
            aw[j][0] = fmaf(qj, (XV).x, aw[j][0]);                             \
            aw[j][1] = fmaf(qj, (XV).y, aw[j][1]);                             \
            aw[j][2] = fmaf(qj, (XV).z, aw[j][2]);                             \
            aw[j][3] = fmaf(qj, (XV).w, aw[j][3]);                             \
            ax[j][0] = fmaf(qj, x2x, ax[j][0]);                                \
            ax[j][1] = fmaf(qj, x2y, ax[j][1]);                                \
            ax[j][2] = fmaf(qj, x2z, ax[j][2]);                                \
            ax[j][3] = fmaf(qj, x2w, ax[j][3]);                                \
        }                                                                      \
    }

    float4 xc = *(const float4*)(Xb + (size_t)nbase * DD + col0);
#pragma unroll 1
    for (int i = 0; i < 64; i += 2) {
        int na = nbase + i * 2;
        int nb_ = nbase + (i + 1) * 2;
        float4 xn = *(const float4*)(Xb + (size_t)nb_ * DD + col0);
        const float* q0 = qb + (size_t)na * PP;    // wave-uniform -> s_load
        MSTEP_FMA(xc, q0)
        int i2 = (i + 2 < 64) ? i + 2 : 0;         // wrap: harmless reload
        xc = *(const float4*)(Xb + (size_t)(nbase + i2 * 2) * DD + col0);
        const float* q1 = qb + (size_t)nb_ * PP;
        MSTEP_FMA(xn, q1)
    }
#undef MSTEP_FMA

    // cross-phase reduction: 2 statically-unrolled passes through padded LDS.
    __shared__ float red[256 * 33]; // 33.8 KB
#define MSTEP_PASS(SRC, DST)                                                   \
    __syncthreads();                                                           \
    if (ph == 1) {                                                             \
        _Pragma("unroll")                                                      \
        for (int jj = 0; jj < 8; jj++)                                         \
            *(float4*)(&red[cg * 33 + jj * 4]) =                               \
                make_float4(SRC[jj][0], SRC[jj][1], SRC[jj][2], SRC[jj][3]);   \
    }                                                                          \
    __syncthreads();                                                           \
    if (ph == 0) {                                                             \
        _Pragma("unroll")                                                      \
        for (int jj = 0; jj < 8; jj++) {                                       \
            float4 o = *(float4*)(&red[cg * 33 + jj * 4]);                     \
            o.x += SRC[jj][0];                                                 \
            o.y += SRC[jj][1];                                                 \
            o.z += SRC[jj][2];                                                 \
            o.w += SRC[jj][3];                                                 \
            *(float4*)(DST + (((size_t)b * 32 + nq) * PP + jbase + jj) * DD +  \
                       col0) = o;                                              \
        }                                                                      \
    }
    MSTEP_PASS(aw, wxp)
    MSTEP_PASS(ax, wxxp)
#undef MSTEP_PASS
}

// ---------------------------------------------------------------------------
// k_finalize: wsum from wsum_p partials; reduce 32 wx/wxx partials -> pi, mu,
// Sigma (d_out) and next-iter W, cns. grid (16 j, 8 b), 256 threads.
// ---------------------------------------------------------------------------
__global__ __launch_bounds__(256) void k_finalize(const float* __restrict__ wsum_p,
                                                  const float* __restrict__ wxp,
                                                  const float* __restrict__ wxxp,
                                                  const float* __restrict__ m,
                                                  const float* __restrict__ V_,
                                                  float* __restrict__ pi,
                                                  float* __restrict__ mu,
                                                  float* __restrict__ Sigma,
                                                  float* __restrict__ Wmat,
                                                  float* __restrict__ cns)
{
    int j = blockIdx.x, b = blockIdx.y;
    int tid = threadIdx.x;
    __shared__ float red[512];
    __shared__ float redw[16 * 17];
    __shared__ float wsr[16];
    __shared__ float sden;
    // wsum: 256 threads = 16 j x 16 chunk-pairs
    {
        int j2 = tid & 15, c2 = tid >> 4;
        float s = wsum_p[((size_t)b * 32 + 2 * c2) * 16 + j2]
                + wsum_p[((size_t)b * 32 + 2 * c2 + 1) * 16 + j2];
        redw[c2 * 17 + j2] = s;
    }
    __syncthreads();
    if (tid < 16) {
        float s = 0.f;
#pragma unroll
        for (int c2 = 0; c2 < 16; c2++) s += redw[c2 * 17 + tid];
        wsr[tid] = s + 1.0f; // + TAU
    }
    __syncthreads();
    if (tid == 0) {
        float dd = 0.f;
#pragma unroll
        for (int jj = 0; jj < 16; jj++) dd += wsr[jj];
        sden = dd;
    }
    __syncthreads();
    float rws = 1.0f / wsr[j];
    float pij = wsr[j] / sden;
    int d0 = tid * 4;
    float wxa[4] = {0, 0, 0, 0}, wxxa[4] = {0, 0, 0, 0};
#pragma unroll
    for (int g = 0; g < 32; g++) {
        const float4 a = *(const float4*)(wxp + (((size_t)b * 32 + g) * PP + j) * DD + d0);
        wxa[0] += a.x; wxa[1] += a.y; wxa[2] += a.z; wxa[3] += a.w;
        const float4 c2 = *(const float4*)(wxxp + (((size_t)b * 32 + g) * PP + j) * DD + d0);
        wxxa[0] += c2.x; wxxa[1] += c2.y; wxxa[2] += c2.z; wxxa[3] += c2.w;
    }
    float4 m4 = *(const float4*)(m + j * DD + d0);
    float4 v4 = *(const float4*)(V_ + j * DD + d0);
    float mvv[4] = {m4.x, m4.y, m4.z, m4.w};
    float vvv[4] = {v4.x, v4.y, v4.z, v4.w};
    float muo[4], sgo[4];
    float llog = 0.f, lmq = 0.f;
    float* Wb = Wmat + (size_t)b * (DD * 32);
#pragma unroll
    for (int c = 0; c < 4; c++) {
        float V = EPSC * log1pf(expf(vvv[c]));
        float muv = (wxa[c] + mvv[c]) * rws;                       // tau = 1
        float Sg = (wxxa[c] + V + mvv[c] * mvv[c]) * rws - muv * muv;
        float inv = 1.0f / Sg;
        muo[c] = muv; sgo[c] = Sg;
        int d = d0 + c;
        Wb[d * 32 + j * 2] = inv;
        Wb[d * 32 + j * 2 + 1] = muv * inv;
        llog += logf(Sg);
        lmq += muv * muv * inv;
    }
    *(float4*)(mu + ((size_t)b * PP + j) * DD + d0) = make_float4(muo[0], muo[1], muo[2], muo[3]);
    *(float4*)(Sigma + ((size_t)b * PP + j) * DD + d0) = make_float4(sgo[0], sgo[1], sgo[2], sgo[3]);
    red[tid] = llog; red[256 + tid] = lmq;
    __syncthreads();
    for (int s = 128; s > 0; s >>= 1) {
        if (tid < s) { red[tid] += red[tid + s]; red[256 + tid] += red[256 + tid + s]; }
        __syncthreads();
    }
    if (tid == 0) {
        pi[b * PP + j] = pij;
        cns[b * PP + j] = logf(pij) - 0.5f * (DLOG2PI + red[0] + red[256]);
    }
}

extern "C" void kernel_launch(void* const* d_in, const int* in_sizes, int n_in,
                              void* d_out, int out_size, void* d_ws, size_t ws_size,
                              hipStream_t stream)
{
    (void)in_sizes; (void)n_in; (void)out_size; (void)ws_size;
    const float* data = (const float*)d_in[0];
    const float* mask = (const float*)d_in[1];
    const float* m    = (const float*)d_in[2];
    const float* V_   = (const float*)d_in[3];

    float* out = (float*)d_out;
    float* pi  = out;                       // 128
    float* mu  = out + 128;                 // 131072
    float* Sg  = out + 128 + 131072;        // 131072
    float* qq  = out + 128 + 2 * 131072;    // 524288

    float* ws     = (float*)d_ws;
    float* Wmat   = ws;                        // 8*1024*32              = 262144
    float* cns    = ws + 262144;               // 128
    float* epart  = ws + 262272;               // 8ks*8b*4096*16         = 4194304
    float* wxp    = ws + 262272 + 4194304;     // 8b*32nq*16*1024        = 4194304
    float* wxxp   = ws + 262272 + 2 * 4194304;
    float* wsum_p = ws + 262272 + 3 * 4194304; // 8b*32*16               = 4096

    k_init<<<dim3(16, 8), 256, 0, stream>>>(m, V_, Wmat, cns);
    for (int it = 0; it < 3; it++) {
        k_estep<<<dim3(16, KS, 8), 256, 0, stream>>>(data, Wmat, epart);
        k_ereduce<<<dim3(32, 8), 128, 0, stream>>>(epart, mask, cns, qq, wsum_p);
        k_mstep<<<dim3(2, 32, 8), 512, 0, stream>>>(data, qq, wxp, wxxp);
        k_finalize<<<dim3(16, 8), 256, 0, stream>>>(wsum_p, wxp, wxxp, m, V_, pi, mu, Sg, Wmat, cns);
    }
}

// Round 7
// 484.696 us; speedup vs baseline: 1.2292x; 1.2292x over previous
//
#include <hip/hip_runtime.h>
#include <math.h>

#define BB 8
#define NN 4096
#define DD 1024
#define PP 16
#define KS 8           // k-split for e-step
#define KC (DD / KS)   // 128 k per chunk
#define KT 32          // k-tile staged in LDS

static constexpr float DLOG2PI = 1881.9861160031696f; // 1024 * log(2*pi)
static constexpr float EPSC = 0.1f;

// W layout: Wmat[b][k][32] interleaved pairs: [j*2]=invS_j(k), [j*2+1]=mu_j(k)*invS_j(k)
// Wmat/qq accesses in hot kernels are wave-uniform -> scalar (s_load) path.
// NOTE (R3): never take a pointer/reference to per-thread accumulator arrays
// — address-taking forces them to scratch (VGPR=32 + GBs of spill).
// NOTE (R6): estep's per-thread-row X reads were 64-way scattered per wave
// instruction (lanes 4 KB apart) — occupancy-invariant ~18% VALUBusy. Fix =
// coalesced LDS staging. Also: j-splitting doubles X traffic (FETCH 75->200MB)
// — never split the broadcast-operand dimension across blocks.

#define FELEM(v, c) ((c) == 0 ? (v).x : (c) == 1 ? (v).y : (c) == 2 ? (v).z : (v).w)

// ---------------------------------------------------------------------------
// k_init: build Wmat + cns[b][j] = log pi - 0.5*(d log2pi + sum log S + sum mu^2/S)
// grid (16 j, 8 b), 256 threads (4 d each)
// ---------------------------------------------------------------------------
__global__ __launch_bounds__(256) void k_init(const float* __restrict__ m,
                                              const float* __restrict__ V_,
                                              float* __restrict__ Wmat,
                                              float* __restrict__ cns)
{
    int j = blockIdx.x, b = blockIdx.y;
    int tid = threadIdx.x;
    __shared__ float red[512];
    int d0 = tid * 4;
    float4 m4 = *(const float4*)(m + j * DD + d0);
    float4 v4 = *(const float4*)(V_ + j * DD + d0);
    float mv[4] = {m4.x, m4.y, m4.z, m4.w};
    float vv[4] = {v4.x, v4.y, v4.z, v4.w};
    float* Wb = Wmat + (size_t)b * (DD * 32);
    float llog = 0.f, lmq = 0.f;
#pragma unroll
    for (int c = 0; c < 4; c++) {
        float V = EPSC * log1pf(expf(vv[c]));
        float inv = 1.0f / V;
        int d = d0 + c;
        Wb[d * 32 + j * 2] = inv;
        Wb[d * 32 + j * 2 + 1] = mv[c] * inv;
        llog += logf(V);
        lmq += mv[c] * mv[c] * inv;
    }
    red[tid] = llog; red[256 + tid] = lmq;
    __syncthreads();
    for (int s = 128; s > 0; s >>= 1) {
        if (tid < s) { red[tid] += red[tid + s]; red[256 + tid] += red[256 + tid + s]; }
        __syncthreads();
    }
    if (tid == 0)
        cns[b * PP + j] = logf(1.0f / 16.0f) - 0.5f * (DLOG2PI + red[0] + red[256]);
}

// ---------------------------------------------------------------------------
// k_estep: X staged via LDS (coalesced global loads; stride-33 pad -> both
// staging writes and compute reads are 2-way bank aliasing = free).
// Thread owns one row (all 16 j), one 128-k chunk, tiles of 32 k.
// W via s_load on the scalar pipe. grid (16 rb, 8 ks, 8 b) = 1024 blocks, 256 thr.
// writes epart[ks][b][n][16] = -0.5*S1 + S2 partial.
// ---------------------------------------------------------------------------
__global__ __launch_bounds__(256) void k_estep(const float* __restrict__ X,
                                               const float* __restrict__ Wmat,
                                               float* __restrict__ epart)
{
    int rb = blockIdx.x, ks = blockIdx.y, b = blockIdx.z;
    int tid = threadIdx.x;
    int n0 = rb * 256;
    const float* Xb = X + ((size_t)b * NN + n0) * DD + ks * KC;
    const float* wp = Wmat + (size_t)b * (DD * 32) + (size_t)(ks * KC) * 32;
    __shared__ float xs[256 * 33];   // 33.8 KB: [row][33] padded
    int srow = tid >> 3;             // staging: 8 lanes per row
    int sch = tid & 7;               // 16-B chunk within the 32-k tile
    float acc1[16] = {0,0,0,0,0,0,0,0,0,0,0,0,0,0,0,0};
    float acc2[16] = {0,0,0,0,0,0,0,0,0,0,0,0,0,0,0,0};
#pragma unroll 1
    for (int t = 0; t < KC / KT; t++) {
        __syncthreads();
        // stage 256 rows x 32 k: thread loads 8 coalesced float4s
#pragma unroll
        for (int i = 0; i < 8; i++) {
            int row = srow + i * 32;
            float4 v = *(const float4*)(Xb + (size_t)row * DD + t * KT + sch * 4);
            xs[row * 33 + sch * 4 + 0] = v.x;   // b32 stores: stride-33 keeps
            xs[row * 33 + sch * 4 + 1] = v.y;   // banks 2-way (free), b128
            xs[row * 33 + sch * 4 + 2] = v.z;   // would be misaligned anyway
            xs[row * 33 + sch * 4 + 3] = v.w;
        }
        __syncthreads();
        const float* wt = wp + (size_t)(t * KT) * 32;
#pragma unroll 8
        for (int k = 0; k < KT; k++) {
            float x = xs[tid * 33 + k];
            float xq = x * x;
            const float* wk = wt + k * 32;   // wave-uniform -> s_load
#pragma unroll
            for (int j = 0; j < 16; j++) {
                acc1[j] = fmaf(xq, wk[2 * j],     acc1[j]);
                acc2[j] = fmaf(x,  wk[2 * j + 1], acc2[j]);
            }
        }
    }
    float* ep = epart + (((size_t)ks * BB + b) * NN + n0 + tid) * PP;
#pragma unroll
    for (int q = 0; q < 4; q++) {
        float4 v = make_float4(-0.5f * acc1[q * 4 + 0] + acc2[q * 4 + 0],
                               -0.5f * acc1[q * 4 + 1] + acc2[q * 4 + 1],
                               -0.5f * acc1[q * 4 + 2] + acc2[q * 4 + 2],
                               -0.5f * acc1[q * 4 + 3] + acc2[q * 4 + 3]);
        *(float4*)(ep + q * 4) = v;
    }
}

// ---------------------------------------------------------------------------
// k_ereduce: sum KS k-partials + cns, softmax over 16 j, * mask -> qq.
// Also emits per-block wsum partial wsum_p[b][chunk][16].
// grid (32 chunks of 128 rows, 8 b), 128 threads (1 row each)
// ---------------------------------------------------------------------------
__global__ __launch_bounds__(128) void k_ereduce(const float* __restrict__ epart,
                                                 const float* __restrict__ mask,
                                                 const float* __restrict__ cns,
                                                 float* __restrict__ qq,
                                                 float* __restrict__ wsum_p)
{
    int chunk = blockIdx.x, b = blockIdx.y;
    int tid = threadIdx.x;
    int n = chunk * 128 + tid;
    __shared__ float cs[16];
    __shared__ float red[128 * 17];
    if (tid < 16) cs[tid] = cns[b * PP + tid];
    __syncthreads();
    float jl[16];
#pragma unroll
    for (int q = 0; q < 4; q++) {
        float4 v = *(const float4*)(epart + ((size_t)b * NN + n) * PP + q * 4);
        jl[q * 4 + 0] = v.x; jl[q * 4 + 1] = v.y; jl[q * 4 + 2] = v.z; jl[q * 4 + 3] = v.w;
    }
#pragma unroll
    for (int ks = 1; ks < KS; ks++) {
#pragma unroll
        for (int q = 0; q < 4; q++) {
            float4 v = *(const float4*)(epart + (((size_t)ks * BB + b) * NN + n) * PP + q * 4);
            jl[q * 4 + 0] += v.x; jl[q * 4 + 1] += v.y; jl[q * 4 + 2] += v.z; jl[q * 4 + 3] += v.w;
        }
    }
    float mx = -3.4e38f;
#pragma unroll
    for (int j = 0; j < 16; j++) { jl[j] += cs[j]; mx = fmaxf(mx, jl[j]); }
    float sum = 0.f;
#pragma unroll
    for (int j = 0; j < 16; j++) { jl[j] = expf(jl[j] - mx); sum += jl[j]; }
    float r = mask[(size_t)b * NN + n] / sum;
    float* qo = qq + ((size_t)b * NN + n) * PP;
#pragma unroll
    for (int q = 0; q < 4; q++) {
        float4 v = make_float4(jl[q * 4 + 0] * r, jl[q * 4 + 1] * r,
                               jl[q * 4 + 2] * r, jl[q * 4 + 3] * r);
        *(float4*)(qo + q * 4) = v;
        red[tid * 17 + q * 4 + 0] = v.x;
        red[tid * 17 + q * 4 + 1] = v.y;
        red[tid * 17 + q * 4 + 2] = v.z;
        red[tid * 17 + q * 4 + 3] = v.w;
    }
    __syncthreads();
    if (tid < 16) {
        float s = 0.f;
#pragma unroll 8
        for (int t = 0; t < 128; t++) s += red[t * 17 + tid];
        wsum_p[((size_t)b * 32 + chunk) * 16 + tid] = s;
    }
}

// ---------------------------------------------------------------------------
// k_mstep: NO LDS in hot loop (X loads are naturally coalesced here).
// Block of 512: all 1024 cols x 2 n-phases, 16 j. qq wave-uniform -> s_load.
// 128 accs/thread, explicit X double-buffer.
// grid (32 nq of 128 rows, 8 b) = 256 blocks.
// ---------------------------------------------------------------------------
__global__ __launch_bounds__(512) void k_mstep(const float* __restrict__ X,
                                               const float* __restrict__ qq,
                                               float* __restrict__ wxp,
                                               float* __restrict__ wxxp)
{
    int nq = blockIdx.x, b = blockIdx.y;
    int tid = threadIdx.x;
    int cg = tid & 255;      // col group: 4 cols
    int ph = tid >> 8;       // 0/1 (wave-uniform)
    int col0 = cg * 4;
    const float* Xb = X + (size_t)b * NN * DD;
    const float* qb = qq + (size_t)b * NN * PP;
    int nbase = nq * 128 + ph;
    float aw[16][4] = {};
    float ax[16][4] = {};

#define MSTEP_FMA(XV, QP)                                                      \
    {                                                                          \
        float x2x = (XV).x * (XV).x, x2y = (XV).y * (XV).y;                    \
        float x2z = (XV).z * (XV).z, x2w = (XV).w * (XV).w;                    \
        _Pragma("unroll")                                                      \
        for (int j = 0; j < 16; j++) {                                         \
            float qj = (QP)[j];                                                \
            aw[j][0] = fmaf(qj, (XV).x, aw[j][0]);                             \
            aw[j][1] = fmaf(qj, (XV).y, aw[j][1]);                             \
            aw[j][2] = fmaf(qj, (XV).z, aw[j][2]);                             \
            aw[j][3] = fmaf(qj, (XV).w, aw[j][3]);                             \
            ax[j][0] = fmaf(qj, x2x, ax[j][0]);                                \
            ax[j][1] = fmaf(qj, x2y, ax[j][1]);                                \
            ax[j][2] = fmaf(qj, x2z, ax[j][2]);                                \
            ax[j][3] = fmaf(qj, x2w, ax[j][3]);                                \
        }                                                                      \
    }

    float4 xc = *(const float4*)(Xb + (size_t)nbase * DD + col0);
#pragma unroll 1
    for (int i = 0; i < 64; i += 2) {
        int na = nbase + i * 2;
        int nb_ = nbase + (i + 1) * 2;
        float4 xn = *(const float4*)(Xb + (size_t)nb_ * DD + col0);
        const float* q0 = qb + (size_t)na * PP;    // wave-uniform -> s_load
        MSTEP_FMA(xc, q0)
        int i2 = (i + 2 < 64) ? i + 2 : 0;         // wrap: harmless reload
        xc = *(const float4*)(Xb + (size_t)(nbase + i2 * 2) * DD + col0);
        const float* q1 = qb + (size_t)nb_ * PP;
        MSTEP_FMA(xn, q1)
    }
#undef MSTEP_FMA

    // cross-phase reduction: 4 statically-unrolled passes through padded LDS.
    __shared__ float red[256 * 33]; // 33.8 KB
#define MSTEP_PASS(SRC, JB, DST)                                               \
    __syncthreads();                                                           \
    if (ph == 1) {                                                             \
        _Pragma("unroll")                                                      \
        for (int jj = 0; jj < 8; jj++)                                         \
            *(float4*)(&red[cg * 33 + jj * 4]) =                               \
                make_float4(SRC[(JB) + jj][0], SRC[(JB) + jj][1],              \
                            SRC[(JB) + jj][2], SRC[(JB) + jj][3]);             \
    }                                                                          \
    __syncthreads();                                                           \
    if (ph == 0) {                                                             \
        _Pragma("unroll")                                                      \
        for (int jj = 0; jj < 8; jj++) {                                       \
            float4 o = *(float4*)(&red[cg * 33 + jj * 4]);                     \
            o.x += SRC[(JB) + jj][0];                                          \
            o.y += SRC[(JB) + jj][1];                                          \
            o.z += SRC[(JB) + jj][2];                                          \
            o.w += SRC[(JB) + jj][3];                                          \
            *(float4*)(DST + (((size_t)b * 32 + nq) * PP + (JB) + jj) * DD +   \
                       col0) = o;                                              \
        }                                                                      \
    }
    MSTEP_PASS(aw, 0, wxp)
    MSTEP_PASS(aw, 8, wxp)
    MSTEP_PASS(ax, 0, wxxp)
    MSTEP_PASS(ax, 8, wxxp)
#undef MSTEP_PASS
}

// ---------------------------------------------------------------------------
// k_finalize: wsum from wsum_p partials; reduce 32 wx/wxx partials -> pi, mu,
// Sigma (d_out) and next-iter W, cns. grid (16 j, 8 b), 256 threads.
// ---------------------------------------------------------------------------
__global__ __launch_bounds__(256) void k_finalize(const float* __restrict__ wsum_p,
                                                  const float* __restrict__ wxp,
                                                  const float* __restrict__ wxxp,
                                                  const float* __restrict__ m,
                                                  const float* __restrict__ V_,
                                                  float* __restrict__ pi,
                                                  float* __restrict__ mu,
                                                  float* __restrict__ Sigma,
                                                  float* __restrict__ Wmat,
                                                  float* __restrict__ cns)
{
    int j = blockIdx.x, b = blockIdx.y;
    int tid = threadIdx.x;
    __shared__ float red[512];
    __shared__ float redw[16 * 17];
    __shared__ float wsr[16];
    __shared__ float sden;
    // wsum: 256 threads = 16 j x 16 chunk-pairs
    {
        int j2 = tid & 15, c2 = tid >> 4;
        float s = wsum_p[((size_t)b * 32 + 2 * c2) * 16 + j2]
                + wsum_p[((size_t)b * 32 + 2 * c2 + 1) * 16 + j2];
        redw[c2 * 17 + j2] = s;
    }
    __syncthreads();
    if (tid < 16) {
        float s = 0.f;
#pragma unroll
        for (int c2 = 0; c2 < 16; c2++) s += redw[c2 * 17 + tid];
        wsr[tid] = s + 1.0f; // + TAU
    }
    __syncthreads();
    if (tid == 0) {
        float dd = 0.f;
#pragma unroll
        for (int jj = 0; jj < 16; jj++) dd += wsr[jj];
        sden = dd;
    }
    __syncthreads();
    float rws = 1.0f / wsr[j];
    float pij = wsr[j] / sden;
    int d0 = tid * 4;
    float wxa[4] = {0, 0, 0, 0}, wxxa[4] = {0, 0, 0, 0};
#pragma unroll
    for (int g = 0; g < 32; g++) {
        const float4 a = *(const float4*)(wxp + (((size_t)b * 32 + g) * PP + j) * DD + d0);
        wxa[0] += a.x; wxa[1] += a.y; wxa[2] += a.z; wxa[3] += a.w;
        const float4 c2 = *(const float4*)(wxxp + (((size_t)b * 32 + g) * PP + j) * DD + d0);
        wxxa[0] += c2.x; wxxa[1] += c2.y; wxxa[2] += c2.z; wxxa[3] += c2.w;
    }
    float4 m4 = *(const float4*)(m + j * DD + d0);
    float4 v4 = *(const float4*)(V_ + j * DD + d0);
    float mvv[4] = {m4.x, m4.y, m4.z, m4.w};
    float vvv[4] = {v4.x, v4.y, v4.z, v4.w};
    float muo[4], sgo[4];
    float llog = 0.f, lmq = 0.f;
    float* Wb = Wmat + (size_t)b * (DD * 32);
#pragma unroll
    for (int c = 0; c < 4; c++) {
        float V = EPSC * log1pf(expf(vvv[c]));
        float muv = (wxa[c] + mvv[c]) * rws;                       // tau = 1
        float Sg = (wxxa[c] + V + mvv[c] * mvv[c]) * rws - muv * muv;
        float inv = 1.0f / Sg;
        muo[c] = muv; sgo[c] = Sg;
        int d = d0 + c;
        Wb[d * 32 + j * 2] = inv;
        Wb[d * 32 + j * 2 + 1] = muv * inv;
        llog += logf(Sg);
        lmq += muv * muv * inv;
    }
    *(float4*)(mu + ((size_t)b * PP + j) * DD + d0) = make_float4(muo[0], muo[1], muo[2], muo[3]);
    *(float4*)(Sigma + ((size_t)b * PP + j) * DD + d0) = make_float4(sgo[0], sgo[1], sgo[2], sgo[3]);
    red[tid] = llog; red[256 + tid] = lmq;
    __syncthreads();
    for (int s = 128; s > 0; s >>= 1) {
        if (tid < s) { red[tid] += red[tid + s]; red[256 + tid] += red[256 + tid + s]; }
        __syncthreads();
    }
    if (tid == 0) {
        pi[b * PP + j] = pij;
        cns[b * PP + j] = logf(pij) - 0.5f * (DLOG2PI + red[0] + red[256]);
    }
}

extern "C" void kernel_launch(void* const* d_in, const int* in_sizes, int n_in,
                              void* d_out, int out_size, void* d_ws, size_t ws_size,
                              hipStream_t stream)
{
    (void)in_sizes; (void)n_in; (void)out_size; (void)ws_size;
    const float* data = (const float*)d_in[0];
    const float* mask = (const float*)d_in[1];
    const float* m    = (const float*)d_in[2];
    const float* V_   = (const float*)d_in[3];

    float* out = (float*)d_out;
    float* pi  = out;                       // 128
    float* mu  = out + 128;                 // 131072
    float* Sg  = out + 128 + 131072;        // 131072
    float* qq  = out + 128 + 2 * 131072;    // 524288

    float* ws     = (float*)d_ws;
    float* Wmat   = ws;                        // 8*1024*32              = 262144
    float* cns    = ws + 262144;               // 128
    float* epart  = ws + 262272;               // 8ks*8b*4096*16         = 4194304
    float* wxp    = ws + 262272 + 4194304;     // 8b*32nq*16*1024        = 4194304
    float* wxxp   = ws + 262272 + 2 * 4194304;
    float* wsum_p = ws + 262272 + 3 * 4194304; // 8b*32*16               = 4096

    k_init<<<dim3(16, 8), 256, 0, stream>>>(m, V_, Wmat, cns);
    for (int it = 0; it < 3; it++) {
        k_estep<<<dim3(16, KS, 8), 256, 0, stream>>>(data, Wmat, epart);
        k_ereduce<<<dim3(32, 8), 128, 0, stream>>>(epart, mask, cns, qq, wsum_p);
        k_mstep<<<dim3(32, 8), 512, 0, stream>>>(data, qq, wxp, wxxp);
        k_finalize<<<dim3(16, 8), 256, 0, stream>>>(wsum_p, wxp, wxxp, m, V_, pi, mu, Sg, Wmat, cns);
    }
}